// Round 7
// baseline (593.759 us; speedup 1.0000x reference)
//
#include <hip/hip_runtime.h>
#include <hip/hip_bf16.h>
#include <math.h>

#define D 64
#define PADS 96   // padded-CSR stride; P(deg>96) ~ 1e-30 for Poisson(16)

typedef __attribute__((ext_vector_type(8))) short bf16x8;
typedef __attribute__((ext_vector_type(8))) _Float16 f16x8;
typedef __attribute__((ext_vector_type(8))) unsigned short u16x8;
typedef __attribute__((ext_vector_type(4))) float f32x4;
typedef unsigned short u16;

__device__ __forceinline__ float gelu_erf(float x) {
    return 0.5f * x * (1.0f + erff(x * 0.70710678118654752f));
}
__device__ __forceinline__ float gelu_tanh(float x) {
    float u = x * fmaf(x * x, 0.035677408136f, 0.7978845608028654f);
    float e = __expf(2.0f * u);
    float th = 1.0f - 2.0f / (e + 1.0f);
    return 0.5f * x * (1.0f + th);
}
__device__ __forceinline__ u16 f2bf(float v) {
    __hip_bfloat16 h = __float2bfloat16(v);
    return *(u16*)&h;
}
__device__ __forceinline__ float bf2f(u16 v) {
    return __uint_as_float(((unsigned int)v) << 16);
}
__device__ __forceinline__ u16 f2h(float v) {
    _Float16 h = (_Float16)v;
    return __builtin_bit_cast(u16, h);
}
// pos p holds dim pi(p) = (p&3)*16 + (p>>2)   (dim t*16+c <-> pos c*4+t)
__device__ __forceinline__ int pi_perm(int p) { return ((p & 3) << 4) | (p >> 2); }

// ---- K1: weight B-fragment packing (blocks 0..11) + padded-CSR scatter (rest)
__global__ __launch_bounds__(256) void prep_scatter(
    const float* __restrict__ Wt, const float* __restrict__ Wq,
    const float* __restrict__ Wks, const float* __restrict__ Wkd,
    const float* __restrict__ Wvs, const float* __restrict__ Wvd,
    u16* __restrict__ WtB, u16* __restrict__ WqB,
    u16* __restrict__ WksB, u16* __restrict__ WkdB,
    u16* __restrict__ WvsB, u16* __restrict__ WvdB,
    const int* __restrict__ ei, const float* __restrict__ et,
    const float* __restrict__ esame,
    int* __restrict__ cursor, int2* __restrict__ pad, int E)
{
    if (blockIdx.x < 12) {
        int task = blockIdx.x * 4 + (threadIdx.x >> 6);  // 0..47
        int lane = threadIdx.x & 63;
        int wsel = task >> 3, f = task & 7;
        int c = lane & 15, quad = lane >> 4;
        int nt = f >> 1, kk = f & 1;
        for (int j = 0; j < 8; ++j) {
            int n = nt * 16 + c, k = kk * 32 + quad * 8 + j;
            float v; u16* dp; bool h16 = false;
            switch (wsel) {
                case 0: v = Wt[n * 65 + k];  dp = WtB;  break;
                case 1: v = Wq[n * 64 + k];  dp = WqB;  break;
                case 2: v = Wks[k * 64 + n]; dp = WksB; break;
                case 3: v = Wkd[k * 64 + n]; dp = WkdB; break;
                case 4: v = Wvs[n * 64 + pi_perm(k)]; dp = WvsB; h16 = true; break;
                default: v = Wvd[n * 64 + pi_perm(k)]; dp = WvdB; h16 = true; break;
            }
            dp[(f * 64 + lane) * 8 + j] = h16 ? f2h(v) : f2bf(v);
        }
    } else {
        int gid = (blockIdx.x - 12) * 256 + threadIdx.x;
        int stride = (gridDim.x - 12) * 256;
        for (int e = gid; e < E; e += stride) {
            int dst = ei[E + e];
            int pos = atomicAdd(&cursor[dst], 1);
            if (pos < PADS) {
                int sv = ei[e];
                if (esame[e] > 0.5f) sv |= 0x80000000;
                pad[(long)dst * PADS + pos] = make_int2(sv, __float_as_int(et[e]));
            }
        }
    }
}

// ---- K2: fused LN + q-chain (all-MFMA): xn = LN(x) -> xnb (bf16);
//      q = xn@Wq^T + bq ; qks/qkd = q@Wk{s,d} stored PI-PERMUTED bf16;
//      bqs = q.bks ; bqd = q.bkd      (16 nodes per wave)
__global__ __launch_bounds__(256) void qgemm(
    const float* __restrict__ x, const float* __restrict__ gamma, const float* __restrict__ beta,
    const u16* __restrict__ WqB, const u16* __restrict__ WksB, const u16* __restrict__ WkdB,
    const float* __restrict__ bq, const float* __restrict__ bks, const float* __restrict__ bkd,
    u16* __restrict__ xnb, u16* __restrict__ qksb, u16* __restrict__ qkdb,
    float* __restrict__ bqs, float* __restrict__ bqd, int N)
{
    __shared__ u16 qtile[4][16 * 64];
    __shared__ u16 stile[4][2][16 * 64];
    const int lane = threadIdx.x & 63;
    const int c = lane & 15, quad = lane >> 4;
    const int w = threadIdx.x >> 6;
    const int wave = blockIdx.x * 4 + w;
    const int n0r = wave * 16;
    const bool active = n0r < N;
    const int n0 = active ? n0r : 0;
    const int rowA = (n0 + c < N) ? n0 + c : N - 1;

    // ---- fused LayerNorm in A-fragment layout ----
    const float* xrow = x + (long)rowA * D;
    f32x4 xa = *(const f32x4*)(xrow + quad * 8);
    f32x4 xb = *(const f32x4*)(xrow + quad * 8 + 4);
    f32x4 xc = *(const f32x4*)(xrow + 32 + quad * 8);
    f32x4 xd = *(const f32x4*)(xrow + 32 + quad * 8 + 4);
    float s = 0.f, s2 = 0.f;
    #pragma unroll
    for (int j = 0; j < 4; ++j) {
        s += xa[j] + xb[j] + xc[j] + xd[j];
        s2 += xa[j] * xa[j] + xb[j] * xb[j] + xc[j] * xc[j] + xd[j] * xd[j];
    }
    s += __shfl_xor(s, 16);  s += __shfl_xor(s, 32);
    s2 += __shfl_xor(s2, 16); s2 += __shfl_xor(s2, 32);
    float mu = s * (1.0f / 64.0f);
    float var = s2 * (1.0f / 64.0f) - mu * mu;
    float rinv = rsqrtf(var + 1e-5f);
    f32x4 ga = *(const f32x4*)(gamma + quad * 8);
    f32x4 gb = *(const f32x4*)(gamma + quad * 8 + 4);
    f32x4 gc = *(const f32x4*)(gamma + 32 + quad * 8);
    f32x4 gd = *(const f32x4*)(gamma + 32 + quad * 8 + 4);
    f32x4 ba = *(const f32x4*)(beta + quad * 8);
    f32x4 bb = *(const f32x4*)(beta + quad * 8 + 4);
    f32x4 bc = *(const f32x4*)(beta + 32 + quad * 8);
    f32x4 bd = *(const f32x4*)(beta + 32 + quad * 8 + 4);
    bf16x8 a0, a1;
    #pragma unroll
    for (int j = 0; j < 4; ++j) {
        a0[j]     = (short)f2bf(fmaf((xa[j] - mu) * rinv, ga[j], ba[j]));
        a0[4 + j] = (short)f2bf(fmaf((xb[j] - mu) * rinv, gb[j], bb[j]));
        a1[j]     = (short)f2bf(fmaf((xc[j] - mu) * rinv, gc[j], bc[j]));
        a1[4 + j] = (short)f2bf(fmaf((xd[j] - mu) * rinv, gd[j], bd[j]));
    }
    *(bf16x8*)(xnb + (long)rowA * D + quad * 8) = a0;
    *(bf16x8*)(xnb + (long)rowA * D + 32 + quad * 8) = a1;

    float bqc[4], bksc[4], bkdc[4];
    #pragma unroll
    for (int t = 0; t < 4; ++t) {
        bqc[t] = bq[t * 16 + c]; bksc[t] = bks[t * 16 + c]; bkdc[t] = bkd[t * 16 + c];
    }

    // GEMM1: q
    f32x4 accq[4];
    #pragma unroll
    for (int t = 0; t < 4; ++t) {
        bf16x8 b0 = *(const bf16x8*)(WqB + ((t * 2 + 0) * 64 + lane) * 8);
        bf16x8 b1 = *(const bf16x8*)(WqB + ((t * 2 + 1) * 64 + lane) * 8);
        f32x4 z = {0.f, 0.f, 0.f, 0.f};
        z = __builtin_amdgcn_mfma_f32_16x16x32_bf16(a0, b0, z, 0, 0, 0);
        z = __builtin_amdgcn_mfma_f32_16x16x32_bf16(a1, b1, z, 0, 0, 0);
        accq[t] = z;
    }
    #pragma unroll
    for (int r = 0; r < 4; ++r) {
        float qv[4], ss = 0.f, sd = 0.f;
        #pragma unroll
        for (int t = 0; t < 4; ++t) {
            qv[t] = accq[t][r] + bqc[t];
            ss = fmaf(qv[t], bksc[t], ss);
            sd = fmaf(qv[t], bkdc[t], sd);
        }
        #pragma unroll
        for (int o = 1; o < 16; o <<= 1) { ss += __shfl_xor(ss, o); sd += __shfl_xor(sd, o); }
        int nrow = n0 + quad * 4 + r;
        if (active && c == 0 && nrow < N) { bqs[nrow] = ss; bqd[nrow] = sd; }
        #pragma unroll
        for (int t = 0; t < 4; ++t)
            qtile[w][(quad * 4 + r) * 64 + t * 16 + c] = f2bf(qv[t]);
    }
    __syncthreads();

    // GEMM2: qks / qkd -> stored pi-permuted (pos c*4+t holds dim t*16+c)
    const u16* qrow = &qtile[w][c * 64 + quad * 8];
    bf16x8 q0 = *(const bf16x8*)(qrow);
    bf16x8 q1 = *(const bf16x8*)(qrow + 32);
    #pragma unroll
    for (int t = 0; t < 4; ++t) {
        bf16x8 bs0 = *(const bf16x8*)(WksB + ((t * 2 + 0) * 64 + lane) * 8);
        bf16x8 bs1 = *(const bf16x8*)(WksB + ((t * 2 + 1) * 64 + lane) * 8);
        bf16x8 bd0 = *(const bf16x8*)(WkdB + ((t * 2 + 0) * 64 + lane) * 8);
        bf16x8 bd1 = *(const bf16x8*)(WkdB + ((t * 2 + 1) * 64 + lane) * 8);
        f32x4 zs = {0.f, 0.f, 0.f, 0.f}, zd = {0.f, 0.f, 0.f, 0.f};
        zs = __builtin_amdgcn_mfma_f32_16x16x32_bf16(q0, bs0, zs, 0, 0, 0);
        zs = __builtin_amdgcn_mfma_f32_16x16x32_bf16(q1, bs1, zs, 0, 0, 0);
        zd = __builtin_amdgcn_mfma_f32_16x16x32_bf16(q0, bd0, zd, 0, 0, 0);
        zd = __builtin_amdgcn_mfma_f32_16x16x32_bf16(q1, bd1, zd, 0, 0, 0);
        #pragma unroll
        for (int r = 0; r < 4; ++r) {
            stile[w][0][(quad * 4 + r) * 64 + c * 4 + t] = f2bf(zs[r]);
            stile[w][1][(quad * 4 + r) * 64 + c * 4 + t] = f2bf(zd[r]);
        }
    }
    __builtin_amdgcn_s_barrier();
    if (active) {
        if (n0 + 16 <= N) {
            const u16x8* s0p = (const u16x8*)&stile[w][0][0];
            const u16x8* s1p = (const u16x8*)&stile[w][1][0];
            u16x8* d0p = (u16x8*)(qksb + (long)n0 * D);
            u16x8* d1p = (u16x8*)(qkdb + (long)n0 * D);
            d0p[2 * lane] = s0p[2 * lane];
            d0p[2 * lane + 1] = s0p[2 * lane + 1];
            d1p[2 * lane] = s1p[2 * lane];
            d1p[2 * lane + 1] = s1p[2 * lane + 1];
        } else {
            for (int i = lane; i < (N - n0) * D; i += 64) {
                qksb[(long)n0 * D + i] = stile[w][0][i];
                qkdb[(long)n0 * D + i] = stile[w][1][i];
            }
        }
    }
}

// ---- K3: fused edge pass + LDS aggregation + value-GEMM + output.
// One wave owns 16 dsts; iterates their padded-CSR edges 16 at a time (MFMA xt),
// accumulates ex*xt into wave-private LDS (pi-permuted, stride 68), then
// aggr = inv*(accs@Wvs^T + accd@Wvd^T) + (ds*inv)*bvs + (dd*inv)*bvd via MFMA,
// out = x + gelu(aggr).  No global atomics anywhere.
__global__ __launch_bounds__(256) void edge_fused(
    const int2* __restrict__ pad, const int* __restrict__ cursor,
    const u16* __restrict__ xnb, const u16* __restrict__ WtB,
    const float* __restrict__ Wt, const float* __restrict__ bt,
    const u16* __restrict__ qksb, const u16* __restrict__ qkdb,
    const float* __restrict__ bqs, const float* __restrict__ bqd,
    const u16* __restrict__ WvsB, const u16* __restrict__ WvdB,
    const float* __restrict__ bvs, const float* __restrict__ bvd,
    const float* __restrict__ x, float* __restrict__ out, int N)
{
    __shared__ float accs[4][16 * 68];   // stride 68: breaks 64-word bank aliasing
    __shared__ float accd[4][16 * 68];
    __shared__ float dsum[4][2][16];
    const int lane = threadIdx.x & 63;
    const int c = lane & 15, quad = lane >> 4;
    const int w = threadIdx.x >> 6;
    const int wave = blockIdx.x * 4 + w;
    const int n0 = wave * 16;

    for (int i = lane; i < 16 * 68; i += 64) { accs[w][i] = 0.f; accd[w][i] = 0.f; }
    if (lane < 16) { dsum[w][0][lane] = 0.f; dsum[w][1][lane] = 0.f; }

    bf16x8 bfrag[8];
    #pragma unroll
    for (int f = 0; f < 8; ++f)
        bfrag[f] = *(const bf16x8*)(WtB + (f * 64 + lane) * 8);

    float btc[4], w64c[4], dva[4];
    #pragma unroll
    for (int t = 0; t < 4; ++t) {
        int dim = t * 16 + c;
        btc[t] = bt[dim];
        w64c[t] = Wt[dim * 65 + 64];
        dva[t] = 200.0f * expf(-9.210340371976184f * (float)(2 * (dim >> 1)) * (1.0f / 64.0f));
    }
    const float phoff = (c & 1) ? 1.5707963267948966f : 0.0f;  // cos = sin(x+pi/2)

    // degrees of this wave's 16 dsts + inclusive scan over the 16-lane group
    int nc = n0 + c;
    int deg = (nc < N) ? min(cursor[nc], PADS) : 0;
    int cum = deg;
    #pragma unroll
    for (int o = 1; o < 16; o <<= 1) {
        int v = __shfl_up(cum, o, 16);
        if (c >= o) cum += v;
    }
    const int total = __shfl(cum, 15, 16);
    const int prevb = cum - deg;   // exclusive prefix for dst n0+c

    for (int off = 0; off < total; off += 16) {
        int m = off + c;
        int mm = (m < total) ? m : total - 1;
        // segment search: dl = count of k with cum[k] <= mm
        int dl = 0;
        #pragma unroll
        for (int k = 0; k < 16; ++k) dl += (mm >= __shfl(cum, k, 16)) ? 1 : 0;
        int idx = mm - __shfl(prevb, dl & 15, 16);
        int2 ev = pad[(long)(n0 + dl) * PADS + idx];
        int sv = ev.x;
        float tv = __int_as_float(ev.y);
        int src = sv & 0x7fffffff;

        const u16* ar = xnb + (long)src * D + quad * 8;
        bf16x8 a0 = *(const bf16x8*)(ar);
        bf16x8 a1 = *(const bf16x8*)(ar + 32);

        f32x4 acc[4];
        #pragma unroll
        for (int t = 0; t < 4; ++t) {
            f32x4 z = {0.f, 0.f, 0.f, 0.f};
            z = __builtin_amdgcn_mfma_f32_16x16x32_bf16(a0, bfrag[t * 2 + 0], z, 0, 0, 0);
            z = __builtin_amdgcn_mfma_f32_16x16x32_bf16(a1, bfrag[t * 2 + 1], z, 0, 0, 0);
            acc[t] = z;
        }

        #pragma unroll
        for (int r = 0; r < 4; ++r) {
            int m2 = quad * 4 + r;
            int dlm = __shfl(dl, m2, 16);
            float tm = __shfl(tv, m2, 16);
            int svm = __shfl(sv, m2, 16);
            bool same = svm < 0;
            bool vm = (off + m2) < total;

            const u16* qrow = (same ? qksb : qkdb) + (long)(n0 + dlm) * D + c * 4;
            ushort4 q4 = *(const ushort4*)qrow;

            float xtv[4];
            #pragma unroll
            for (int t = 0; t < 4; ++t) {
                float v = gelu_tanh(acc[t][r] + fmaf(tm, w64c[t], btc[t]));
                v += __sinf(fmaf(tm, dva[t], phoff));
                xtv[t] = v;
            }
            float p = xtv[0] * bf2f(q4.x);
            p = fmaf(xtv[1], bf2f(q4.y), p);
            p = fmaf(xtv[2], bf2f(q4.z), p);
            p = fmaf(xtv[3], bf2f(q4.w), p);
            #pragma unroll
            for (int o = 1; o < 16; o <<= 1) p += __shfl_xor(p, o);
            float bqv = same ? bqs[n0 + dlm] : bqd[n0 + dlm];
            float ex = vm ? __expf((p + bqv) * 0.125f) : 0.0f;

            float* ap = (same ? accs[w] : accd[w]) + dlm * 68 + c * 4;
            atomicAdd(ap + 0, ex * xtv[0]);
            atomicAdd(ap + 1, ex * xtv[1]);
            atomicAdd(ap + 2, ex * xtv[2]);
            atomicAdd(ap + 3, ex * xtv[3]);
            if (c == 0) atomicAdd(&dsum[w][same ? 0 : 1][dlm], ex);
        }
    }
    __syncthreads();

    // ---- value GEMM from LDS accumulators (A row m = c, k = pos) ----
    const float* sr = &accs[w][c * 68 + quad * 8];
    const float* dr = &accd[w][c * 68 + quad * 8];
    f16x8 s0, s1, d0, d1;
    #pragma unroll
    for (int j = 0; j < 8; ++j) {
        s0[j] = (_Float16)sr[j];
        s1[j] = (_Float16)sr[32 + j];
        d0[j] = (_Float16)dr[j];
        d1[j] = (_Float16)dr[32 + j];
    }
    f32x4 oacc[4];
    #pragma unroll
    for (int t = 0; t < 4; ++t) {
        f16x8 bs0 = *(const f16x8*)(WvsB + ((t * 2 + 0) * 64 + lane) * 8);
        f16x8 bs1 = *(const f16x8*)(WvsB + ((t * 2 + 1) * 64 + lane) * 8);
        f16x8 bd0 = *(const f16x8*)(WvdB + ((t * 2 + 0) * 64 + lane) * 8);
        f16x8 bd1 = *(const f16x8*)(WvdB + ((t * 2 + 1) * 64 + lane) * 8);
        f32x4 z = {0.f, 0.f, 0.f, 0.f};
        z = __builtin_amdgcn_mfma_f32_16x16x32_f16(s0, bs0, z, 0, 0, 0);
        z = __builtin_amdgcn_mfma_f32_16x16x32_f16(s1, bs1, z, 0, 0, 0);
        z = __builtin_amdgcn_mfma_f32_16x16x32_f16(d0, bd0, z, 0, 0, 0);
        z = __builtin_amdgcn_mfma_f32_16x16x32_f16(d1, bd1, z, 0, 0, 0);
        oacc[t] = z;
    }
    float bvsc[4], bvdc[4];
    #pragma unroll
    for (int t = 0; t < 4; ++t) { bvsc[t] = bvs[t * 16 + c]; bvdc[t] = bvd[t * 16 + c]; }

    #pragma unroll
    for (int r = 0; r < 4; ++r) {
        int n = n0 + quad * 4 + r;
        if (n >= N) continue;
        float ds = dsum[w][0][quad * 4 + r], dd = dsum[w][1][quad * 4 + r];
        float inv = 1.0f / (ds + dd + 1e-16f);
        float fs = ds * inv, fd = dd * inv;
        #pragma unroll
        for (int t = 0; t < 4; ++t) {
            long idx = (long)n * D + t * 16 + c;
            float o = fmaf(oacc[t][r], inv, fmaf(fs, bvsc[t], fd * bvdc[t]));
            out[idx] = x[idx] + gelu_erf(o);
        }
    }
}

extern "C" void kernel_launch(void* const* d_in, const int* in_sizes, int n_in,
                              void* d_out, int out_size, void* d_ws, size_t ws_size,
                              hipStream_t stream) {
    const float* x        = (const float*)d_in[0];
    const int*   ei       = (const int*)d_in[1];
    const float* et       = (const float*)d_in[2];
    const float* esame    = (const float*)d_in[4];
    const float* ln_gamma = (const float*)d_in[5];
    const float* ln_beta  = (const float*)d_in[6];
    const float* Wt  = (const float*)d_in[7];
    const float* bt  = (const float*)d_in[8];
    const float* Wq  = (const float*)d_in[9];
    const float* bq  = (const float*)d_in[10];
    const float* Wks = (const float*)d_in[11];
    const float* bks = (const float*)d_in[12];
    const float* Wkd = (const float*)d_in[13];
    const float* bkd = (const float*)d_in[14];
    const float* Wvs = (const float*)d_in[15];
    const float* bvs = (const float*)d_in[16];
    const float* Wvd = (const float*)d_in[17];
    const float* bvd = (const float*)d_in[18];
    float* out = (float*)d_out;

    const int N = in_sizes[0] / D;   // 50000
    const int E = in_sizes[2];       // 800000

    // workspace layout (8B-aligned first)
    int2* pad   = (int2*)d_ws;                    // N*96*8B = 38.4 MB
    int* cursor = (int*)(pad + (long)N * PADS);   // N ints
    float* bqs  = (float*)(cursor + N);
    float* bqd  = bqs + N;
    u16* xnb  = (u16*)(bqd + N);                  // N*64 bf16
    u16* qksb = xnb + (long)N * D;                // N*64 bf16 (pi-permuted)
    u16* qkdb = qksb + (long)N * D;
    u16* WtB  = qkdb + (long)N * D;               // 4096 u16 each
    u16* WqB  = WtB + 4096;
    u16* WksB = WqB + 4096;
    u16* WkdB = WksB + 4096;
    u16* WvsB = WkdB + 4096;
    u16* WvdB = WvsB + 4096;

    hipMemsetAsync(cursor, 0, (size_t)N * sizeof(int), stream);

    prep_scatter<<<12 + 512, 256, 0, stream>>>(Wt, Wq, Wks, Wkd, Wvs, Wvd,
                                               WtB, WqB, WksB, WkdB, WvsB, WvdB,
                                               ei, et, esame, cursor, pad, E);
    const int nblk16 = ((N + 15) / 16 + 3) / 4;
    qgemm<<<nblk16, 256, 0, stream>>>(x, ln_gamma, ln_beta, WqB, WksB, WkdB,
                                      bq, bks, bkd, xnb, qksb, qkdb, bqs, bqd, N);
    edge_fused<<<(N + 63) / 64, 256, 0, stream>>>(pad, cursor, xnb, WtB, Wt, bt,
                                                  qksb, qkdb, bqs, bqd,
                                                  WvsB, WvdB, bvs, bvd, x, out, N);
}

// Round 8
// 442.550 us; speedup vs baseline: 1.3417x; 1.3417x over previous
//
#include <hip/hip_runtime.h>
#include <hip/hip_bf16.h>
#include <math.h>

#define D 64

typedef __attribute__((ext_vector_type(8))) short bf16x8;
typedef __attribute__((ext_vector_type(8))) _Float16 f16x8;
typedef __attribute__((ext_vector_type(8))) unsigned short u16x8;
typedef __attribute__((ext_vector_type(4))) float f32x4;
typedef unsigned short u16;

__device__ __forceinline__ float gelu_erf(float x) {
    return 0.5f * x * (1.0f + erff(x * 0.70710678118654752f));
}
__device__ __forceinline__ float gelu_tanh(float x) {
    float u = x * fmaf(x * x, 0.035677408136f, 0.7978845608028654f);
    float e = __expf(2.0f * u);
    float th = 1.0f - 2.0f / (e + 1.0f);
    return 0.5f * x * (1.0f + th);
}
__device__ __forceinline__ u16 f2bf(float v) {
    __hip_bfloat16 h = __float2bfloat16(v);
    return *(u16*)&h;
}
__device__ __forceinline__ float bf2f(u16 v) {
    return __uint_as_float(((unsigned int)v) << 16);
}
__device__ __forceinline__ u16 f2h(float v) {
    _Float16 h = (_Float16)v;
    return __builtin_bit_cast(u16, h);
}
__device__ __forceinline__ void atomic_pk_add_f16(u16* addr, float lo, float hi) {
    unsigned int p = (unsigned int)f2h(lo) | ((unsigned int)f2h(hi) << 16);
    asm volatile("global_atomic_pk_add_f16 %0, %1, off sc1" :: "v"(addr), "v"(p));
}
// pos p holds dim pi(p) = (p&3)*16 + (p>>2)
__device__ __forceinline__ int pi_perm(int p) { return ((p & 3) << 4) | (p >> 2); }

// ---- K1: weight B-fragment packing (blocks 0..11) + key histogram (rest)
// key = 2*dst + (same ? 0 : 1)
__global__ __launch_bounds__(256) void prep_hist(
    const float* __restrict__ Wt, const float* __restrict__ Wq,
    const float* __restrict__ Wks, const float* __restrict__ Wkd,
    const float* __restrict__ Wvs, const float* __restrict__ Wvd,
    u16* __restrict__ WtB, u16* __restrict__ WqB,
    u16* __restrict__ WksB, u16* __restrict__ WkdB,
    u16* __restrict__ WvsB, u16* __restrict__ WvdB,
    const int* __restrict__ ei, const float* __restrict__ esame,
    int* __restrict__ cnt, int E)
{
    if (blockIdx.x < 12) {
        int task = blockIdx.x * 4 + (threadIdx.x >> 6);  // 0..47
        int lane = threadIdx.x & 63;
        int wsel = task >> 3, f = task & 7;
        int c = lane & 15, quad = lane >> 4;
        int nt = f >> 1, kk = f & 1;
        for (int j = 0; j < 8; ++j) {
            int n = nt * 16 + c, k = kk * 32 + quad * 8 + j;
            float v; u16* dp; bool h16 = false;
            switch (wsel) {
                case 0: v = Wt[n * 65 + k];  dp = WtB;  break;
                case 1: v = Wq[n * 64 + k];  dp = WqB;  break;
                case 2: v = Wks[k * 64 + n]; dp = WksB; break;
                case 3: v = Wkd[k * 64 + n]; dp = WkdB; break;
                case 4: v = Wvs[n * 64 + pi_perm(k)]; dp = WvsB; h16 = true; break;
                default: v = Wvd[n * 64 + pi_perm(k)]; dp = WvdB; h16 = true; break;
            }
            dp[(f * 64 + lane) * 8 + j] = h16 ? f2h(v) : f2bf(v);
        }
    } else {
        int gid = (blockIdx.x - 12) * 256 + threadIdx.x;
        int stride = (gridDim.x - 12) * 256;
        for (int e = gid; e < E; e += stride) {
            int key = 2 * ei[E + e] + (esame[e] > 0.5f ? 0 : 1);
            atomicAdd(&cnt[key], 1);
        }
    }
}

// ---- K2: exclusive scan of cnt[0..M) -> cursor
__global__ __launch_bounds__(1024) void scan_kernel(const int* __restrict__ cnt,
                                                    int* __restrict__ cursor, int M)
{
    __shared__ int part[1024];
    int tid = threadIdx.x;
    int chunk = (M + 1023) >> 10;
    int lo = tid * chunk, hi = min(lo + chunk, M);
    int s = 0;
    for (int i = lo; i < hi; ++i) s += cnt[i];
    part[tid] = s;
    __syncthreads();
    for (int o = 1; o < 1024; o <<= 1) {
        int v = (tid >= o) ? part[tid - o] : 0;
        __syncthreads();
        part[tid] += v;
        __syncthreads();
    }
    int base = (tid == 0) ? 0 : part[tid - 1];
    for (int i = lo; i < hi; ++i) {
        cursor[i] = base;
        base += cnt[i];
    }
}

// ---- K3: counting-sort scatter into (ev = (src, t), keyv) ordered by key
__global__ void scatter_kernel(const int* __restrict__ ei, const float* __restrict__ et,
                               const float* __restrict__ esame, int* __restrict__ cursor,
                               int2* __restrict__ ev, int* __restrict__ keyv, int E)
{
    int stride = gridDim.x * blockDim.x;
    for (int e = blockIdx.x * blockDim.x + threadIdx.x; e < E; e += stride) {
        int key = 2 * ei[E + e] + (esame[e] > 0.5f ? 0 : 1);
        int pos = atomicAdd(&cursor[key], 1);
        ev[pos] = make_int2(ei[e], __float_as_int(et[e]));
        keyv[pos] = key;
    }
}

// ---- K4: fused LN + q-chain (all-MFMA). qk2[key] rows (pi-permuted bf16),
//      bq2[key] scalars. key even = same (Wks), odd = diff (Wkd).
__global__ __launch_bounds__(256) void qgemm(
    const float* __restrict__ x, const float* __restrict__ gamma, const float* __restrict__ beta,
    const u16* __restrict__ WqB, const u16* __restrict__ WksB, const u16* __restrict__ WkdB,
    const float* __restrict__ bq, const float* __restrict__ bks, const float* __restrict__ bkd,
    u16* __restrict__ xnb, u16* __restrict__ qk2, float* __restrict__ bq2, int N)
{
    __shared__ u16 qtile[4][16 * 64];
    __shared__ u16 stile[4][32 * 64];
    const int lane = threadIdx.x & 63;
    const int c = lane & 15, quad = lane >> 4;
    const int w = threadIdx.x >> 6;
    const int wave = blockIdx.x * 4 + w;
    const int n0r = wave * 16;
    const bool active = n0r < N;
    const int n0 = active ? n0r : 0;
    const int rowA = (n0 + c < N) ? n0 + c : N - 1;

    // fused LayerNorm in A-fragment layout
    const float* xrow = x + (long)rowA * D;
    f32x4 xa = *(const f32x4*)(xrow + quad * 8);
    f32x4 xb = *(const f32x4*)(xrow + quad * 8 + 4);
    f32x4 xc = *(const f32x4*)(xrow + 32 + quad * 8);
    f32x4 xd = *(const f32x4*)(xrow + 32 + quad * 8 + 4);
    float s = 0.f, s2 = 0.f;
    #pragma unroll
    for (int j = 0; j < 4; ++j) {
        s += xa[j] + xb[j] + xc[j] + xd[j];
        s2 += xa[j] * xa[j] + xb[j] * xb[j] + xc[j] * xc[j] + xd[j] * xd[j];
    }
    s += __shfl_xor(s, 16);  s += __shfl_xor(s, 32);
    s2 += __shfl_xor(s2, 16); s2 += __shfl_xor(s2, 32);
    float mu = s * (1.0f / 64.0f);
    float var = s2 * (1.0f / 64.0f) - mu * mu;
    float rinv = rsqrtf(var + 1e-5f);
    f32x4 ga = *(const f32x4*)(gamma + quad * 8);
    f32x4 gb = *(const f32x4*)(gamma + quad * 8 + 4);
    f32x4 gc = *(const f32x4*)(gamma + 32 + quad * 8);
    f32x4 gd = *(const f32x4*)(gamma + 32 + quad * 8 + 4);
    f32x4 ba = *(const f32x4*)(beta + quad * 8);
    f32x4 bb = *(const f32x4*)(beta + quad * 8 + 4);
    f32x4 bc = *(const f32x4*)(beta + 32 + quad * 8);
    f32x4 bd = *(const f32x4*)(beta + 32 + quad * 8 + 4);
    bf16x8 a0, a1;
    #pragma unroll
    for (int j = 0; j < 4; ++j) {
        a0[j]     = (short)f2bf(fmaf((xa[j] - mu) * rinv, ga[j], ba[j]));
        a0[4 + j] = (short)f2bf(fmaf((xb[j] - mu) * rinv, gb[j], bb[j]));
        a1[j]     = (short)f2bf(fmaf((xc[j] - mu) * rinv, gc[j], bc[j]));
        a1[4 + j] = (short)f2bf(fmaf((xd[j] - mu) * rinv, gd[j], bd[j]));
    }
    *(bf16x8*)(xnb + (long)rowA * D + quad * 8) = a0;
    *(bf16x8*)(xnb + (long)rowA * D + 32 + quad * 8) = a1;

    float bqc[4], bksc[4], bkdc[4];
    #pragma unroll
    for (int t = 0; t < 4; ++t) {
        bqc[t] = bq[t * 16 + c]; bksc[t] = bks[t * 16 + c]; bkdc[t] = bkd[t * 16 + c];
    }

    // GEMM1: q
    f32x4 accq[4];
    #pragma unroll
    for (int t = 0; t < 4; ++t) {
        bf16x8 b0 = *(const bf16x8*)(WqB + ((t * 2 + 0) * 64 + lane) * 8);
        bf16x8 b1 = *(const bf16x8*)(WqB + ((t * 2 + 1) * 64 + lane) * 8);
        f32x4 z = {0.f, 0.f, 0.f, 0.f};
        z = __builtin_amdgcn_mfma_f32_16x16x32_bf16(a0, b0, z, 0, 0, 0);
        z = __builtin_amdgcn_mfma_f32_16x16x32_bf16(a1, b1, z, 0, 0, 0);
        accq[t] = z;
    }
    #pragma unroll
    for (int r = 0; r < 4; ++r) {
        float qv[4], ss = 0.f, sd = 0.f;
        #pragma unroll
        for (int t = 0; t < 4; ++t) {
            qv[t] = accq[t][r] + bqc[t];
            ss = fmaf(qv[t], bksc[t], ss);
            sd = fmaf(qv[t], bkdc[t], sd);
        }
        #pragma unroll
        for (int o = 1; o < 16; o <<= 1) { ss += __shfl_xor(ss, o); sd += __shfl_xor(sd, o); }
        int nrow = n0 + quad * 4 + r;
        if (active && c == 0 && nrow < N)
            *(float2*)(bq2 + 2 * nrow) = make_float2(ss, sd);
        #pragma unroll
        for (int t = 0; t < 4; ++t)
            qtile[w][(quad * 4 + r) * 64 + t * 16 + c] = f2bf(qv[t]);
    }
    __syncthreads();

    // GEMM2: qks/qkd -> stile rows (2m, 2m+1), pi-permuted positions
    const u16* qrow = &qtile[w][c * 64 + quad * 8];
    bf16x8 q0 = *(const bf16x8*)(qrow);
    bf16x8 q1 = *(const bf16x8*)(qrow + 32);
    #pragma unroll
    for (int t = 0; t < 4; ++t) {
        bf16x8 bs0 = *(const bf16x8*)(WksB + ((t * 2 + 0) * 64 + lane) * 8);
        bf16x8 bs1 = *(const bf16x8*)(WksB + ((t * 2 + 1) * 64 + lane) * 8);
        bf16x8 bd0 = *(const bf16x8*)(WkdB + ((t * 2 + 0) * 64 + lane) * 8);
        bf16x8 bd1 = *(const bf16x8*)(WkdB + ((t * 2 + 1) * 64 + lane) * 8);
        f32x4 zs = {0.f, 0.f, 0.f, 0.f}, zd = {0.f, 0.f, 0.f, 0.f};
        zs = __builtin_amdgcn_mfma_f32_16x16x32_bf16(q0, bs0, zs, 0, 0, 0);
        zs = __builtin_amdgcn_mfma_f32_16x16x32_bf16(q1, bs1, zs, 0, 0, 0);
        zd = __builtin_amdgcn_mfma_f32_16x16x32_bf16(q0, bd0, zd, 0, 0, 0);
        zd = __builtin_amdgcn_mfma_f32_16x16x32_bf16(q1, bd1, zd, 0, 0, 0);
        #pragma unroll
        for (int r = 0; r < 4; ++r) {
            int m = quad * 4 + r;
            stile[w][(2 * m + 0) * 64 + c * 4 + t] = f2bf(zs[r]);
            stile[w][(2 * m + 1) * 64 + c * 4 + t] = f2bf(zd[r]);
        }
    }
    __syncthreads();
    if (active) {
        int nrows = min(16, N - n0);
        const u16x8* sp = (const u16x8*)&stile[w][0];
        u16x8* dp = (u16x8*)(qk2 + (long)(2 * n0) * D);
        int cnt8 = nrows * 16;   // 2*nrows rows * 8 vec/row
        for (int j = lane; j < cnt8; j += 64) dp[j] = sp[j];
    }
}

// ---- K5: edge pass over key-sorted edges. Each quad owns a contiguous
// substream (chunk/4 edges); run-accumulates per key in registers; one
// pk-f16 atomic pair + den atomic per run flush.
__global__ __launch_bounds__(256) void edge_pass(
    const int2* __restrict__ ev, const int* __restrict__ keyv,
    const u16* __restrict__ xnb, const u16* __restrict__ WtB,
    const float* __restrict__ Wt, const float* __restrict__ bt,
    const u16* __restrict__ qk2, const float* __restrict__ bq2,
    u16* __restrict__ A, float* __restrict__ den, int E, int chunk)
{
    const int lane = threadIdx.x & 63;
    const int c = lane & 15, quad = lane >> 4;
    const int wave = blockIdx.x * 4 + (threadIdx.x >> 6);
    const long base = (long)wave * chunk;
    if (base >= E) return;
    const long end = (base + chunk < (long)E) ? base + chunk : (long)E;
    const int qchunk = chunk >> 2;

    bf16x8 bfrag[8];
    #pragma unroll
    for (int f = 0; f < 8; ++f)
        bfrag[f] = *(const bf16x8*)(WtB + (f * 64 + lane) * 8);

    float btc[4], w64c[4], dva[4];
    #pragma unroll
    for (int t = 0; t < 4; ++t) {
        int dim = t * 16 + c;
        btc[t] = bt[dim];
        w64c[t] = Wt[dim * 65 + 64];
        dva[t] = 200.0f * expf(-9.210340371976184f * (float)(2 * (dim >> 1)) * (1.0f / 64.0f));
    }
    const float phoff = (c & 1) ? 1.5707963267948966f : 0.0f;

    int cur_key = -1;
    float racc0 = 0.f, racc1 = 0.f, racc2 = 0.f, racc3 = 0.f, rden = 0.f;
    ushort4 q4 = {0, 0, 0, 0};
    float bqv = 0.f;

    // row c's substream position: quad (c>>2), offset (c&3)
    const long rowbase = base + (long)(c >> 2) * qchunk + (c & 3);

    for (int i = 0; i < qchunk; i += 4) {
        long eidx = rowbase + i;
        long ec = eidx < end ? eidx : end - 1;
        int2 evv = ev[ec];
        int keyL = keyv[ec];
        int srcL = evv.x;
        float tL = __int_as_float(evv.y);

        const u16* ar = xnb + (long)srcL * D + quad * 8;
        bf16x8 a0 = *(const bf16x8*)(ar);
        bf16x8 a1 = *(const bf16x8*)(ar + 32);

        f32x4 acc[4];
        #pragma unroll
        for (int t = 0; t < 4; ++t) {
            f32x4 z = {0.f, 0.f, 0.f, 0.f};
            z = __builtin_amdgcn_mfma_f32_16x16x32_bf16(a0, bfrag[t * 2 + 0], z, 0, 0, 0);
            z = __builtin_amdgcn_mfma_f32_16x16x32_bf16(a1, bfrag[t * 2 + 1], z, 0, 0, 0);
            acc[t] = z;
        }

        #pragma unroll
        for (int r = 0; r < 4; ++r) {
            int m = quad * 4 + r;
            int keym = __shfl(keyL, m);
            float tm = __shfl(tL, m);
            long eglob = base + (long)quad * qchunk + i + r;
            bool vm = eglob < end;

            float xtv[4];
            #pragma unroll
            for (int t = 0; t < 4; ++t) {
                float v = gelu_tanh(acc[t][r] + fmaf(tm, w64c[t], btc[t]));
                v += __sinf(fmaf(tm, dva[t], phoff));
                xtv[t] = v;
            }

            if (keym != cur_key) {
                if (cur_key >= 0) {
                    u16* ap = A + (long)cur_key * D + c * 4;
                    atomic_pk_add_f16(ap, racc0, racc1);
                    atomic_pk_add_f16(ap + 2, racc2, racc3);
                    if (c == 0) atomicAdd(&den[cur_key], rden);
                }
                cur_key = keym;
                q4 = *(const ushort4*)(qk2 + (long)keym * D + c * 4);
                bqv = bq2[keym];
                racc0 = racc1 = racc2 = racc3 = 0.f;
                rden = 0.f;
            }

            float p = xtv[0] * bf2f(q4.x);
            p = fmaf(xtv[1], bf2f(q4.y), p);
            p = fmaf(xtv[2], bf2f(q4.z), p);
            p = fmaf(xtv[3], bf2f(q4.w), p);
            #pragma unroll
            for (int o = 1; o < 16; o <<= 1) p += __shfl_xor(p, o);
            float ex = vm ? __expf((p + bqv) * 0.125f) : 0.0f;

            racc0 = fmaf(ex, xtv[0], racc0);
            racc1 = fmaf(ex, xtv[1], racc1);
            racc2 = fmaf(ex, xtv[2], racc2);
            racc3 = fmaf(ex, xtv[3], racc3);
            if (c == 0) rden += ex;
        }
    }

    if (cur_key >= 0) {
        u16* ap = A + (long)cur_key * D + c * 4;
        atomic_pk_add_f16(ap, racc0, racc1);
        atomic_pk_add_f16(ap + 2, racc2, racc3);
        if (c == 0) atomicAdd(&den[cur_key], rden);
    }
}

// ---- K6: node post. aggr = inv*(A[2n]@Wvs^T + A[2n+1]@Wvd^T)
//          + (den[2n]*inv)*bvs + (den[2n+1]*inv)*bvd ; out = x + gelu(aggr)
__global__ __launch_bounds__(256) void vgemm(
    const float* __restrict__ x, const u16* __restrict__ A, const float* __restrict__ den,
    const u16* __restrict__ WvsB, const u16* __restrict__ WvdB,
    const float* __restrict__ bvs, const float* __restrict__ bvd,
    float* __restrict__ out, int N)
{
    const int lane = threadIdx.x & 63;
    const int c = lane & 15, quad = lane >> 4;
    const int wave = blockIdx.x * 4 + (threadIdx.x >> 6);
    const int n0 = wave * 16;
    if (n0 >= N) return;
    const int rowA = (n0 + c < N) ? n0 + c : N - 1;

    float bvsc[4], bvdc[4];
    #pragma unroll
    for (int t = 0; t < 4; ++t) { bvsc[t] = bvs[t * 16 + c]; bvdc[t] = bvd[t * 16 + c]; }

    const u16* srow = A + (long)(2 * rowA) * D + quad * 8;
    const u16* drow = A + (long)(2 * rowA + 1) * D + quad * 8;
    f16x8 s0 = *(const f16x8*)(srow);
    f16x8 s1 = *(const f16x8*)(srow + 32);
    f16x8 d0 = *(const f16x8*)(drow);
    f16x8 d1 = *(const f16x8*)(drow + 32);

    f32x4 oacc[4];
    #pragma unroll
    for (int t = 0; t < 4; ++t) {
        f16x8 bs0 = *(const f16x8*)(WvsB + ((t * 2 + 0) * 64 + lane) * 8);
        f16x8 bs1 = *(const f16x8*)(WvsB + ((t * 2 + 1) * 64 + lane) * 8);
        f16x8 bd0 = *(const f16x8*)(WvdB + ((t * 2 + 0) * 64 + lane) * 8);
        f16x8 bd1 = *(const f16x8*)(WvdB + ((t * 2 + 1) * 64 + lane) * 8);
        f32x4 z = {0.f, 0.f, 0.f, 0.f};
        z = __builtin_amdgcn_mfma_f32_16x16x32_f16(s0, bs0, z, 0, 0, 0);
        z = __builtin_amdgcn_mfma_f32_16x16x32_f16(s1, bs1, z, 0, 0, 0);
        z = __builtin_amdgcn_mfma_f32_16x16x32_f16(d0, bd0, z, 0, 0, 0);
        z = __builtin_amdgcn_mfma_f32_16x16x32_f16(d1, bd1, z, 0, 0, 0);
        oacc[t] = z;
    }

    #pragma unroll
    for (int r = 0; r < 4; ++r) {
        int n = n0 + quad * 4 + r;
        if (n >= N) continue;
        float ds = den[2 * n], dd = den[2 * n + 1];
        float inv = 1.0f / (ds + dd + 1e-16f);
        float fs = ds * inv, fd = dd * inv;
        #pragma unroll
        for (int t = 0; t < 4; ++t) {
            long idx = (long)n * D + t * 16 + c;
            float o = fmaf(oacc[t][r], inv, fmaf(fs, bvsc[t], fd * bvdc[t]));
            out[idx] = x[idx] + gelu_erf(o);
        }
    }
}

extern "C" void kernel_launch(void* const* d_in, const int* in_sizes, int n_in,
                              void* d_out, int out_size, void* d_ws, size_t ws_size,
                              hipStream_t stream) {
    const float* x        = (const float*)d_in[0];
    const int*   ei       = (const int*)d_in[1];
    const float* et       = (const float*)d_in[2];
    const float* esame    = (const float*)d_in[4];
    const float* ln_gamma = (const float*)d_in[5];
    const float* ln_beta  = (const float*)d_in[6];
    const float* Wt  = (const float*)d_in[7];
    const float* bt  = (const float*)d_in[8];
    const float* Wq  = (const float*)d_in[9];
    const float* bq  = (const float*)d_in[10];
    const float* Wks = (const float*)d_in[11];
    const float* bks = (const float*)d_in[12];
    const float* Wkd = (const float*)d_in[13];
    const float* bkd = (const float*)d_in[14];
    const float* Wvs = (const float*)d_in[15];
    const float* bvs = (const float*)d_in[16];
    const float* Wvd = (const float*)d_in[17];
    const float* bvd = (const float*)d_in[18];
    float* out = (float*)d_out;

    const int N = in_sizes[0] / D;   // 50000
    const int E = in_sizes[2];       // 800000
    const int M = 2 * N;             // key space

    // workspace: [A (M*64 f16)] [den (M f32)] [cnt (M i32)]  <- one memset
    //            [cursor (M i32)] [bq2 (M f32)] [ev (E int2)] [keyv (E i32)]
    //            [xnb (N*64 bf16)] [qk2 (M*64 bf16)] [6x weight frags]
    u16* A      = (u16*)d_ws;
    float* den  = (float*)(A + (long)M * D);
    int* cnt    = (int*)(den + M);
    int* cursor = cnt + M;
    float* bq2  = (float*)(cursor + M);
    int2* ev    = (int2*)(bq2 + M);
    int* keyv   = (int*)(ev + E);
    u16* xnb    = (u16*)(keyv + E);
    u16* qk2    = xnb + (long)N * D;
    u16* WtB    = qk2 + (long)M * D;
    u16* WqB    = WtB + 4096;
    u16* WksB   = WqB + 4096;
    u16* WkdB   = WksB + 4096;
    u16* WvsB   = WkdB + 4096;
    u16* WvdB   = WvsB + 4096;

    // zero A + den + cnt in one shot (contiguous)
    hipMemsetAsync(A, 0, (size_t)M * D * 2 + (size_t)M * 4 * 2, stream);

    prep_hist<<<12 + 488, 256, 0, stream>>>(Wt, Wq, Wks, Wkd, Wvs, Wvd,
                                            WtB, WqB, WksB, WkdB, WvsB, WvdB,
                                            ei, esame, cnt, E);
    scan_kernel<<<1, 1024, 0, stream>>>(cnt, cursor, M);
    scatter_kernel<<<512, 256, 0, stream>>>(ei, et, esame, cursor, ev, keyv, E);

    const int nblk16 = ((N + 15) / 16 + 3) / 4;
    qgemm<<<nblk16, 256, 0, stream>>>(x, ln_gamma, ln_beta, WqB, WksB, WkdB,
                                      bq, bks, bkd, xnb, qk2, bq2, N);

    const int nwaves = 2048 * 4;
    const int chunk = ((E + nwaves * 16 - 1) / (nwaves * 16)) * 16;  // 112 @ E=800k
    edge_pass<<<2048, 256, 0, stream>>>(ev, keyv, xnb, WtB, Wt, bt,
                                        qk2, bq2, A, den, E, chunk);
    vgemm<<<nblk16, 256, 0, stream>>>(x, A, den, WvsB, WvdB, bvs, bvd, out, N);
}

// Round 9
// 293.814 us; speedup vs baseline: 2.0209x; 1.5062x over previous
//
#include <hip/hip_runtime.h>
#include <hip/hip_bf16.h>
#include <math.h>

#define D 64

typedef __attribute__((ext_vector_type(8))) short bf16x8;
typedef __attribute__((ext_vector_type(8))) _Float16 f16x8;
typedef __attribute__((ext_vector_type(8))) unsigned short u16x8;
typedef __attribute__((ext_vector_type(4))) float f32x4;
typedef unsigned short u16;

__device__ __forceinline__ float gelu_erf(float x) {
    return 0.5f * x * (1.0f + erff(x * 0.70710678118654752f));
}
__device__ __forceinline__ float gelu_tanh(float x) {
    float u = x * fmaf(x * x, 0.035677408136f, 0.7978845608028654f);
    float e = __expf(2.0f * u);
    float th = 1.0f - 2.0f / (e + 1.0f);
    return 0.5f * x * (1.0f + th);
}
__device__ __forceinline__ u16 f2bf(float v) {
    __hip_bfloat16 h = __float2bfloat16(v);
    return *(u16*)&h;
}
__device__ __forceinline__ float bf2f(u16 v) {
    return __uint_as_float(((unsigned int)v) << 16);
}
__device__ __forceinline__ u16 f2h(float v) {
    _Float16 h = (_Float16)v;
    return __builtin_bit_cast(u16, h);
}
__device__ __forceinline__ void atomic_pk_add_f16(u16* addr, float lo, float hi) {
    unsigned int p = (unsigned int)f2h(lo) | ((unsigned int)f2h(hi) << 16);
    asm volatile("global_atomic_pk_add_f16 %0, %1, off sc1" :: "v"(addr), "v"(p));
}
// pos p holds dim pi(p) = (p&3)*16 + (p>>2)
__device__ __forceinline__ int pi_perm(int p) { return ((p & 3) << 4) | (p >> 2); }

// ---- K1: weight B-fragment packing (blocks 0..11) + key histogram (rest)
// key = 2*dst + (same ? 0 : 1)
__global__ __launch_bounds__(256) void prep_hist(
    const float* __restrict__ Wt, const float* __restrict__ Wq,
    const float* __restrict__ Wks, const float* __restrict__ Wkd,
    const float* __restrict__ Wvs, const float* __restrict__ Wvd,
    u16* __restrict__ WtB, u16* __restrict__ WqB,
    u16* __restrict__ WksB, u16* __restrict__ WkdB,
    u16* __restrict__ WvsB, u16* __restrict__ WvdB,
    const int* __restrict__ ei, const float* __restrict__ esame,
    int* __restrict__ cnt, int E)
{
    if (blockIdx.x < 12) {
        int task = blockIdx.x * 4 + (threadIdx.x >> 6);  // 0..47
        int lane = threadIdx.x & 63;
        int wsel = task >> 3, f = task & 7;
        int c = lane & 15, quad = lane >> 4;
        int nt = f >> 1, kk = f & 1;
        for (int j = 0; j < 8; ++j) {
            int n = nt * 16 + c, k = kk * 32 + quad * 8 + j;
            float v; u16* dp; bool h16 = false;
            switch (wsel) {
                case 0: v = Wt[n * 65 + k];  dp = WtB;  break;
                case 1: v = Wq[n * 64 + k];  dp = WqB;  break;
                case 2: v = Wks[k * 64 + n]; dp = WksB; break;
                case 3: v = Wkd[k * 64 + n]; dp = WkdB; break;
                case 4: v = Wvs[n * 64 + pi_perm(k)]; dp = WvsB; h16 = true; break;
                default: v = Wvd[n * 64 + pi_perm(k)]; dp = WvdB; h16 = true; break;
            }
            dp[(f * 64 + lane) * 8 + j] = h16 ? f2h(v) : f2bf(v);
        }
    } else {
        int gid = (blockIdx.x - 12) * 256 + threadIdx.x;
        int stride = (gridDim.x - 12) * 256;
        for (int e = gid; e < E; e += stride) {
            int key = 2 * ei[E + e] + (esame[e] > 0.5f ? 0 : 1);
            atomicAdd(&cnt[key], 1);
        }
    }
}

// ---- hierarchical scan: A) per-block reduce, B) scan block sums, C) local scan + offset
#define SCAN_CHUNK 2048

__global__ __launch_bounds__(256) void scan_phaseA(const int* __restrict__ cnt,
                                                   int* __restrict__ bsum, int M)
{
    int base = blockIdx.x * SCAN_CHUNK;
    int s = 0;
    for (int i = threadIdx.x; i < SCAN_CHUNK; i += 256) {
        int idx = base + i;
        s += (idx < M) ? cnt[idx] : 0;
    }
    #pragma unroll
    for (int o = 32; o; o >>= 1) s += __shfl_xor(s, o);
    __shared__ int red[4];
    if ((threadIdx.x & 63) == 0) red[threadIdx.x >> 6] = s;
    __syncthreads();
    if (threadIdx.x == 0) bsum[blockIdx.x] = red[0] + red[1] + red[2] + red[3];
}

__global__ __launch_bounds__(256) void scan_phaseB(int* __restrict__ bsum, int nb)
{
    // in-place exclusive scan of bsum[0..nb), nb <= 256
    __shared__ int tmp[256];
    int v = (threadIdx.x < nb) ? bsum[threadIdx.x] : 0;
    tmp[threadIdx.x] = v;
    __syncthreads();
    if (threadIdx.x == 0) {
        int acc = 0;
        for (int i = 0; i < nb; ++i) { int t = tmp[i]; tmp[i] = acc; acc += t; }
    }
    __syncthreads();
    if (threadIdx.x < nb) bsum[threadIdx.x] = tmp[threadIdx.x];
}

__global__ __launch_bounds__(256) void scan_phaseC(const int* __restrict__ cnt,
                                                   const int* __restrict__ bsum,
                                                   int* __restrict__ cursor, int M)
{
    int base = blockIdx.x * SCAN_CHUNK;
    int i0 = base + threadIdx.x * 8;
    int vals[8];
    int tsum = 0;
    #pragma unroll
    for (int j = 0; j < 8; ++j) {
        int idx = i0 + j;
        vals[j] = (idx < M) ? cnt[idx] : 0;
        tsum += vals[j];
    }
    // exclusive scan of tsum across the block
    int lane = threadIdx.x & 63;
    int w = threadIdx.x >> 6;
    int inc = tsum;
    #pragma unroll
    for (int o = 1; o < 64; o <<= 1) {
        int v = __shfl_up(inc, o);
        if (lane >= o) inc += v;
    }
    __shared__ int wsum[4];
    if (lane == 63) wsum[w] = inc;
    __syncthreads();
    int woff = 0;
    #pragma unroll
    for (int k = 0; k < 4; ++k) woff += (k < w) ? wsum[k] : 0;
    int excl = woff + (inc - tsum) + bsum[blockIdx.x];
    #pragma unroll
    for (int j = 0; j < 8; ++j) {
        int idx = i0 + j;
        if (idx < M) cursor[idx] = excl;
        excl += vals[j];
    }
}

// ---- K3: counting-sort scatter into (ev = (src, t), keyv) ordered by key
__global__ void scatter_kernel(const int* __restrict__ ei, const float* __restrict__ et,
                               const float* __restrict__ esame, int* __restrict__ cursor,
                               int2* __restrict__ ev, int* __restrict__ keyv, int E)
{
    int stride = gridDim.x * blockDim.x;
    for (int e = blockIdx.x * blockDim.x + threadIdx.x; e < E; e += stride) {
        int key = 2 * ei[E + e] + (esame[e] > 0.5f ? 0 : 1);
        int pos = atomicAdd(&cursor[key], 1);
        ev[pos] = make_int2(ei[e], __float_as_int(et[e]));
        keyv[pos] = key;
    }
}

// ---- K4: fused LN + q-chain (all-MFMA). qk2[key] rows (pi-permuted bf16),
//      bq2[key] scalars. key even = same (Wks), odd = diff (Wkd).
__global__ __launch_bounds__(256) void qgemm(
    const float* __restrict__ x, const float* __restrict__ gamma, const float* __restrict__ beta,
    const u16* __restrict__ WqB, const u16* __restrict__ WksB, const u16* __restrict__ WkdB,
    const float* __restrict__ bq, const float* __restrict__ bks, const float* __restrict__ bkd,
    u16* __restrict__ xnb, u16* __restrict__ qk2, float* __restrict__ bq2, int N)
{
    __shared__ u16 qtile[4][16 * 64];
    __shared__ u16 stile[4][32 * 64];
    const int lane = threadIdx.x & 63;
    const int c = lane & 15, quad = lane >> 4;
    const int w = threadIdx.x >> 6;
    const int wave = blockIdx.x * 4 + w;
    const int n0r = wave * 16;
    const bool active = n0r < N;
    const int n0 = active ? n0r : 0;
    const int rowA = (n0 + c < N) ? n0 + c : N - 1;

    // fused LayerNorm in A-fragment layout
    const float* xrow = x + (long)rowA * D;
    f32x4 xa = *(const f32x4*)(xrow + quad * 8);
    f32x4 xb = *(const f32x4*)(xrow + quad * 8 + 4);
    f32x4 xc = *(const f32x4*)(xrow + 32 + quad * 8);
    f32x4 xd = *(const f32x4*)(xrow + 32 + quad * 8 + 4);
    float s = 0.f, s2 = 0.f;
    #pragma unroll
    for (int j = 0; j < 4; ++j) {
        s += xa[j] + xb[j] + xc[j] + xd[j];
        s2 += xa[j] * xa[j] + xb[j] * xb[j] + xc[j] * xc[j] + xd[j] * xd[j];
    }
    s += __shfl_xor(s, 16);  s += __shfl_xor(s, 32);
    s2 += __shfl_xor(s2, 16); s2 += __shfl_xor(s2, 32);
    float mu = s * (1.0f / 64.0f);
    float var = s2 * (1.0f / 64.0f) - mu * mu;
    float rinv = rsqrtf(var + 1e-5f);
    f32x4 ga = *(const f32x4*)(gamma + quad * 8);
    f32x4 gb = *(const f32x4*)(gamma + quad * 8 + 4);
    f32x4 gc = *(const f32x4*)(gamma + 32 + quad * 8);
    f32x4 gd = *(const f32x4*)(gamma + 32 + quad * 8 + 4);
    f32x4 ba = *(const f32x4*)(beta + quad * 8);
    f32x4 bb = *(const f32x4*)(beta + quad * 8 + 4);
    f32x4 bc = *(const f32x4*)(beta + 32 + quad * 8);
    f32x4 bd = *(const f32x4*)(beta + 32 + quad * 8 + 4);
    bf16x8 a0, a1;
    #pragma unroll
    for (int j = 0; j < 4; ++j) {
        a0[j]     = (short)f2bf(fmaf((xa[j] - mu) * rinv, ga[j], ba[j]));
        a0[4 + j] = (short)f2bf(fmaf((xb[j] - mu) * rinv, gb[j], bb[j]));
        a1[j]     = (short)f2bf(fmaf((xc[j] - mu) * rinv, gc[j], bc[j]));
        a1[4 + j] = (short)f2bf(fmaf((xd[j] - mu) * rinv, gd[j], bd[j]));
    }
    *(bf16x8*)(xnb + (long)rowA * D + quad * 8) = a0;
    *(bf16x8*)(xnb + (long)rowA * D + 32 + quad * 8) = a1;

    float bqc[4], bksc[4], bkdc[4];
    #pragma unroll
    for (int t = 0; t < 4; ++t) {
        bqc[t] = bq[t * 16 + c]; bksc[t] = bks[t * 16 + c]; bkdc[t] = bkd[t * 16 + c];
    }

    // GEMM1: q
    f32x4 accq[4];
    #pragma unroll
    for (int t = 0; t < 4; ++t) {
        bf16x8 b0 = *(const bf16x8*)(WqB + ((t * 2 + 0) * 64 + lane) * 8);
        bf16x8 b1 = *(const bf16x8*)(WqB + ((t * 2 + 1) * 64 + lane) * 8);
        f32x4 z = {0.f, 0.f, 0.f, 0.f};
        z = __builtin_amdgcn_mfma_f32_16x16x32_bf16(a0, b0, z, 0, 0, 0);
        z = __builtin_amdgcn_mfma_f32_16x16x32_bf16(a1, b1, z, 0, 0, 0);
        accq[t] = z;
    }
    #pragma unroll
    for (int r = 0; r < 4; ++r) {
        float qv[4], ss = 0.f, sd = 0.f;
        #pragma unroll
        for (int t = 0; t < 4; ++t) {
            qv[t] = accq[t][r] + bqc[t];
            ss = fmaf(qv[t], bksc[t], ss);
            sd = fmaf(qv[t], bkdc[t], sd);
        }
        #pragma unroll
        for (int o = 1; o < 16; o <<= 1) { ss += __shfl_xor(ss, o); sd += __shfl_xor(sd, o); }
        int nrow = n0 + quad * 4 + r;
        if (active && c == 0 && nrow < N)
            *(float2*)(bq2 + 2 * nrow) = make_float2(ss, sd);
        #pragma unroll
        for (int t = 0; t < 4; ++t)
            qtile[w][(quad * 4 + r) * 64 + t * 16 + c] = f2bf(qv[t]);
    }
    __syncthreads();

    // GEMM2: qks/qkd -> stile rows (2m, 2m+1), pi-permuted positions
    const u16* qrow = &qtile[w][c * 64 + quad * 8];
    bf16x8 q0 = *(const bf16x8*)(qrow);
    bf16x8 q1 = *(const bf16x8*)(qrow + 32);
    #pragma unroll
    for (int t = 0; t < 4; ++t) {
        bf16x8 bs0 = *(const bf16x8*)(WksB + ((t * 2 + 0) * 64 + lane) * 8);
        bf16x8 bs1 = *(const bf16x8*)(WksB + ((t * 2 + 1) * 64 + lane) * 8);
        bf16x8 bd0 = *(const bf16x8*)(WkdB + ((t * 2 + 0) * 64 + lane) * 8);
        bf16x8 bd1 = *(const bf16x8*)(WkdB + ((t * 2 + 1) * 64 + lane) * 8);
        f32x4 zs = {0.f, 0.f, 0.f, 0.f}, zd = {0.f, 0.f, 0.f, 0.f};
        zs = __builtin_amdgcn_mfma_f32_16x16x32_bf16(q0, bs0, zs, 0, 0, 0);
        zs = __builtin_amdgcn_mfma_f32_16x16x32_bf16(q1, bs1, zs, 0, 0, 0);
        zd = __builtin_amdgcn_mfma_f32_16x16x32_bf16(q0, bd0, zd, 0, 0, 0);
        zd = __builtin_amdgcn_mfma_f32_16x16x32_bf16(q1, bd1, zd, 0, 0, 0);
        #pragma unroll
        for (int r = 0; r < 4; ++r) {
            int m = quad * 4 + r;
            stile[w][(2 * m + 0) * 64 + c * 4 + t] = f2bf(zs[r]);
            stile[w][(2 * m + 1) * 64 + c * 4 + t] = f2bf(zd[r]);
        }
    }
    __syncthreads();
    if (active) {
        int nrows = min(16, N - n0);
        const u16x8* sp = (const u16x8*)&stile[w][0];
        u16x8* dp = (u16x8*)(qk2 + (long)(2 * n0) * D);
        int cnt8 = nrows * 16;   // 2*nrows rows * 8 vec/row
        for (int j = lane; j < cnt8; j += 64) dp[j] = sp[j];
    }
}

// ---- K5: edge pass over key-sorted edges. Each quad owns a contiguous
// substream (chunk/4 edges); run-accumulates per key in registers; one
// pk-f16 atomic pair + den atomic per run flush.
__global__ __launch_bounds__(256) void edge_pass(
    const int2* __restrict__ ev, const int* __restrict__ keyv,
    const u16* __restrict__ xnb, const u16* __restrict__ WtB,
    const float* __restrict__ Wt, const float* __restrict__ bt,
    const u16* __restrict__ qk2, const float* __restrict__ bq2,
    u16* __restrict__ A, float* __restrict__ den, int E, int chunk)
{
    const int lane = threadIdx.x & 63;
    const int c = lane & 15, quad = lane >> 4;
    const int wave = blockIdx.x * 4 + (threadIdx.x >> 6);
    const long base = (long)wave * chunk;
    if (base >= E) return;
    const long end = (base + chunk < (long)E) ? base + chunk : (long)E;
    const int qchunk = chunk >> 2;

    bf16x8 bfrag[8];
    #pragma unroll
    for (int f = 0; f < 8; ++f)
        bfrag[f] = *(const bf16x8*)(WtB + (f * 64 + lane) * 8);

    float btc[4], w64c[4], dva[4];
    #pragma unroll
    for (int t = 0; t < 4; ++t) {
        int dim = t * 16 + c;
        btc[t] = bt[dim];
        w64c[t] = Wt[dim * 65 + 64];
        dva[t] = 200.0f * expf(-9.210340371976184f * (float)(2 * (dim >> 1)) * (1.0f / 64.0f));
    }
    const float phoff = (c & 1) ? 1.5707963267948966f : 0.0f;

    int cur_key = -1;
    float racc0 = 0.f, racc1 = 0.f, racc2 = 0.f, racc3 = 0.f, rden = 0.f;
    ushort4 q4 = {0, 0, 0, 0};
    float bqv = 0.f;

    // row c's substream position: quad (c>>2), offset (c&3)
    const long rowbase = base + (long)(c >> 2) * qchunk + (c & 3);

    for (int i = 0; i < qchunk; i += 4) {
        long eidx = rowbase + i;
        long ec = eidx < end ? eidx : end - 1;
        int2 evv = ev[ec];
        int keyL = keyv[ec];
        int srcL = evv.x;
        float tL = __int_as_float(evv.y);

        const u16* ar = xnb + (long)srcL * D + quad * 8;
        bf16x8 a0 = *(const bf16x8*)(ar);
        bf16x8 a1 = *(const bf16x8*)(ar + 32);

        f32x4 acc[4];
        #pragma unroll
        for (int t = 0; t < 4; ++t) {
            f32x4 z = {0.f, 0.f, 0.f, 0.f};
            z = __builtin_amdgcn_mfma_f32_16x16x32_bf16(a0, bfrag[t * 2 + 0], z, 0, 0, 0);
            z = __builtin_amdgcn_mfma_f32_16x16x32_bf16(a1, bfrag[t * 2 + 1], z, 0, 0, 0);
            acc[t] = z;
        }

        #pragma unroll
        for (int r = 0; r < 4; ++r) {
            int m = quad * 4 + r;
            int keym = __shfl(keyL, m);
            float tm = __shfl(tL, m);
            long eglob = base + (long)quad * qchunk + i + r;
            bool vm = eglob < end;

            float xtv[4];
            #pragma unroll
            for (int t = 0; t < 4; ++t) {
                float v = gelu_tanh(acc[t][r] + fmaf(tm, w64c[t], btc[t]));
                v += __sinf(fmaf(tm, dva[t], phoff));
                xtv[t] = v;
            }

            if (keym != cur_key) {
                if (cur_key >= 0) {
                    u16* ap = A + (long)cur_key * D + c * 4;
                    atomic_pk_add_f16(ap, racc0, racc1);
                    atomic_pk_add_f16(ap + 2, racc2, racc3);
                    if (c == 0) atomicAdd(&den[cur_key], rden);
                }
                cur_key = keym;
                q4 = *(const ushort4*)(qk2 + (long)keym * D + c * 4);
                bqv = bq2[keym];
                racc0 = racc1 = racc2 = racc3 = 0.f;
                rden = 0.f;
            }

            float p = xtv[0] * bf2f(q4.x);
            p = fmaf(xtv[1], bf2f(q4.y), p);
            p = fmaf(xtv[2], bf2f(q4.z), p);
            p = fmaf(xtv[3], bf2f(q4.w), p);
            #pragma unroll
            for (int o = 1; o < 16; o <<= 1) p += __shfl_xor(p, o);
            float ex = vm ? __expf((p + bqv) * 0.125f) : 0.0f;

            racc0 = fmaf(ex, xtv[0], racc0);
            racc1 = fmaf(ex, xtv[1], racc1);
            racc2 = fmaf(ex, xtv[2], racc2);
            racc3 = fmaf(ex, xtv[3], racc3);
            if (c == 0) rden += ex;
        }
    }

    if (cur_key >= 0) {
        u16* ap = A + (long)cur_key * D + c * 4;
        atomic_pk_add_f16(ap, racc0, racc1);
        atomic_pk_add_f16(ap + 2, racc2, racc3);
        if (c == 0) atomicAdd(&den[cur_key], rden);
    }
}

// ---- K6: node post. aggr = inv*(A[2n]@Wvs^T + A[2n+1]@Wvd^T)
//          + (den[2n]*inv)*bvs + (den[2n+1]*inv)*bvd ; out = x + gelu(aggr)
__global__ __launch_bounds__(256) void vgemm(
    const float* __restrict__ x, const u16* __restrict__ A, const float* __restrict__ den,
    const u16* __restrict__ WvsB, const u16* __restrict__ WvdB,
    const float* __restrict__ bvs, const float* __restrict__ bvd,
    float* __restrict__ out, int N)
{
    const int lane = threadIdx.x & 63;
    const int c = lane & 15, quad = lane >> 4;
    const int wave = blockIdx.x * 4 + (threadIdx.x >> 6);
    const int n0 = wave * 16;
    if (n0 >= N) return;
    const int rowA = (n0 + c < N) ? n0 + c : N - 1;

    float bvsc[4], bvdc[4];
    #pragma unroll
    for (int t = 0; t < 4; ++t) { bvsc[t] = bvs[t * 16 + c]; bvdc[t] = bvd[t * 16 + c]; }

    const u16* srow = A + (long)(2 * rowA) * D + quad * 8;
    const u16* drow = A + (long)(2 * rowA + 1) * D + quad * 8;
    f16x8 s0 = *(const f16x8*)(srow);
    f16x8 s1 = *(const f16x8*)(srow + 32);
    f16x8 d0 = *(const f16x8*)(drow);
    f16x8 d1 = *(const f16x8*)(drow + 32);

    f32x4 oacc[4];
    #pragma unroll
    for (int t = 0; t < 4; ++t) {
        f16x8 bs0 = *(const f16x8*)(WvsB + ((t * 2 + 0) * 64 + lane) * 8);
        f16x8 bs1 = *(const f16x8*)(WvsB + ((t * 2 + 1) * 64 + lane) * 8);
        f16x8 bd0 = *(const f16x8*)(WvdB + ((t * 2 + 0) * 64 + lane) * 8);
        f16x8 bd1 = *(const f16x8*)(WvdB + ((t * 2 + 1) * 64 + lane) * 8);
        f32x4 z = {0.f, 0.f, 0.f, 0.f};
        z = __builtin_amdgcn_mfma_f32_16x16x32_f16(s0, bs0, z, 0, 0, 0);
        z = __builtin_amdgcn_mfma_f32_16x16x32_f16(s1, bs1, z, 0, 0, 0);
        z = __builtin_amdgcn_mfma_f32_16x16x32_f16(d0, bd0, z, 0, 0, 0);
        z = __builtin_amdgcn_mfma_f32_16x16x32_f16(d1, bd1, z, 0, 0, 0);
        oacc[t] = z;
    }

    #pragma unroll
    for (int r = 0; r < 4; ++r) {
        int n = n0 + quad * 4 + r;
        if (n >= N) continue;
        float ds = den[2 * n], dd = den[2 * n + 1];
        float inv = 1.0f / (ds + dd + 1e-16f);
        float fs = ds * inv, fd = dd * inv;
        #pragma unroll
        for (int t = 0; t < 4; ++t) {
            long idx = (long)n * D + t * 16 + c;
            float o = fmaf(oacc[t][r], inv, fmaf(fs, bvsc[t], fd * bvdc[t]));
            out[idx] = x[idx] + gelu_erf(o);
        }
    }
}

extern "C" void kernel_launch(void* const* d_in, const int* in_sizes, int n_in,
                              void* d_out, int out_size, void* d_ws, size_t ws_size,
                              hipStream_t stream) {
    const float* x        = (const float*)d_in[0];
    const int*   ei       = (const int*)d_in[1];
    const float* et       = (const float*)d_in[2];
    const float* esame    = (const float*)d_in[4];
    const float* ln_gamma = (const float*)d_in[5];
    const float* ln_beta  = (const float*)d_in[6];
    const float* Wt  = (const float*)d_in[7];
    const float* bt  = (const float*)d_in[8];
    const float* Wq  = (const float*)d_in[9];
    const float* bq  = (const float*)d_in[10];
    const float* Wks = (const float*)d_in[11];
    const float* bks = (const float*)d_in[12];
    const float* Wkd = (const float*)d_in[13];
    const float* bkd = (const float*)d_in[14];
    const float* Wvs = (const float*)d_in[15];
    const float* bvs = (const float*)d_in[16];
    const float* Wvd = (const float*)d_in[17];
    const float* bvd = (const float*)d_in[18];
    float* out = (float*)d_out;

    const int N = in_sizes[0] / D;   // 50000
    const int E = in_sizes[2];       // 800000
    const int M = 2 * N;             // key space

    u16* A      = (u16*)d_ws;
    float* den  = (float*)(A + (long)M * D);
    int* cnt    = (int*)(den + M);
    int* cursor = cnt + M;
    float* bq2  = (float*)(cursor + M);
    int2* ev    = (int2*)(bq2 + M);
    int* keyv   = (int*)(ev + E);
    int* bsum   = keyv + E;                      // scan block sums (<=256)
    u16* xnb    = (u16*)(bsum + 256);
    u16* qk2    = xnb + (long)N * D;
    u16* WtB    = qk2 + (long)M * D;
    u16* WqB    = WtB + 4096;
    u16* WksB   = WqB + 4096;
    u16* WkdB   = WksB + 4096;
    u16* WvsB   = WkdB + 4096;
    u16* WvdB   = WvsB + 4096;

    // zero A + den + cnt in one shot (contiguous)
    hipMemsetAsync(A, 0, (size_t)M * D * 2 + (size_t)M * 4 * 2, stream);

    prep_hist<<<12 + 488, 256, 0, stream>>>(Wt, Wq, Wks, Wkd, Wvs, Wvd,
                                            WtB, WqB, WksB, WkdB, WvsB, WvdB,
                                            ei, esame, cnt, E);
    const int nbScan = (M + SCAN_CHUNK - 1) / SCAN_CHUNK;   // 49 @ M=100k
    scan_phaseA<<<nbScan, 256, 0, stream>>>(cnt, bsum, M);
    scan_phaseB<<<1, 256, 0, stream>>>(bsum, nbScan);
    scan_phaseC<<<nbScan, 256, 0, stream>>>(cnt, bsum, cursor, M);
    scatter_kernel<<<512, 256, 0, stream>>>(ei, et, esame, cursor, ev, keyv, E);

    const int nblk16 = ((N + 15) / 16 + 3) / 4;
    qgemm<<<nblk16, 256, 0, stream>>>(x, ln_gamma, ln_beta, WqB, WksB, WkdB,
                                      bq, bks, bkd, xnb, qk2, bq2, N);

    const int nwaves = 2048 * 4;
    const int chunk = ((E + nwaves * 16 - 1) / (nwaves * 16)) * 16;  // 112 @ E=800k
    edge_pass<<<2048, 256, 0, stream>>>(ev, keyv, xnb, WtB, Wt, bt,
                                        qk2, bq2, A, den, E, chunk);
    vgemm<<<nblk16, 256, 0, stream>>>(x, A, den, WvsB, WvdB, bvs, bvd, out, N);
}